// Round 14
// baseline (264.642 us; speedup 1.0000x reference)
//
#include <hip/hip_runtime.h>

#define N_NODES 25000
#define N_EDGES 400000
#define IN_CH 1024
#define FC 128
#define ADD_CH 20
#define XCH 148   // FC + ADD
#define MID 37
#define OUT_CH 3
#define MAXDEG 64
#define CSTRIDE 16   // cursor padded to one counter per 64B line

typedef short bf16x8 __attribute__((ext_vector_type(8)));
typedef float f32x4 __attribute__((ext_vector_type(4)));

__device__ __forceinline__ float bflo(unsigned int v) {
    return __builtin_bit_cast(float, v << 16);
}
__device__ __forceinline__ float bfhi(unsigned int v) {
    return __builtin_bit_cast(float, v & 0xffff0000u);
}
// pack 2 f32 -> 2 bf16 (RNE), single VALU op
__device__ __forceinline__ unsigned int cvtpk(float a, float b) {
    unsigned int r;
    asm("v_cvt_pk_bf16_f32 %0, %1, %2" : "=v"(r) : "v"(a), "v"(b));
    return r;
}

// async 16B global->LDS DMA (counts in vmcnt)
__device__ __forceinline__ void gload16(const void* g, void* l) {
    __builtin_amdgcn_global_load_lds(
        (const __attribute__((address_space(1))) unsigned int*)g,
        (__attribute__((address_space(3))) unsigned int*)l,
        16, 0, 0);
}

// ---------------- prep: W swizzle + cursor zero (one dispatch) --------------
#define WSWZ_B 16
#define ZERO_B 49   // 49*512 >= 25000 (each thread zeroes one padded line)

__global__ __launch_bounds__(512) void prep(const float* __restrict__ Wl,
                                            const float* __restrict__ Wr,
                                            ushort* __restrict__ Wpk,
                                            int* __restrict__ cursor) {
    int b = blockIdx.x, t = threadIdx.x;
    if (b < WSWZ_B) {
        int w = t >> 6, lane = t & 63, l15 = lane & 15, q8 = (lane >> 4) * 8;
        int ch = b * 16 + l15;
        const float* src = (ch < FC) ? (Wl + (size_t)ch * IN_CH)
                                     : (Wr + (size_t)(ch - FC) * IN_CH);
        #pragma unroll
        for (int j = 0; j < 4; ++j) {
            int kt = w * 4 + j;
            float4 lo = *(const float4*)(src + kt * 32 + q8);
            float4 hi = *(const float4*)(src + kt * 32 + q8 + 4);
            uint4 pk;
            pk.x = cvtpk(lo.x, lo.y); pk.y = cvtpk(lo.z, lo.w);
            pk.z = cvtpk(hi.x, hi.y); pk.w = cvtpk(hi.z, hi.w);
            ((uint4*)Wpk)[((size_t)kt * 16 + b) * 64 + lane] = pk;
        }
    } else {
        int i = (b - WSWZ_B) * 512 + t;
        if (i < N_NODES) {
            uint4 z = {0, 0, 0, 0};
            uint4* dst = (uint4*)(cursor + (size_t)i * CSTRIDE);
            dst[0] = z; dst[1] = z; dst[2] = z; dst[3] = z;
        }
    }
}

// ---------------- hetero: depth-3 counted-vmcnt GEMM + ILP build ------------
// UNCHANGED (round-8 config, reproduced at 64-66us across 3 runs; locally
// converged after 12 variant rounds bracketed it 62-84us).
#define GEMM_B 391    // ceil(25000/64)
#define BUILD_B 196   // ceil(400000/2048)

__global__ __launch_bounds__(512, 4) void gemm_build(const float* __restrict__ A,
                                                     const ushort* __restrict__ Wpk,
                                                     ushort* __restrict__ Py,
                                                     ushort* __restrict__ Pz,
                                                     const int* __restrict__ edges,
                                                     int* __restrict__ cursor,
                                                     int* __restrict__ col) {
    __shared__ uint4 LDS[3][1536];   // [buf][ 0..1023 = W | 1024..1535 = A ]  72 KB
    int b = blockIdx.x, t = threadIdx.x;
    if (b >= GEMM_B) {
        int base = (b - GEMM_B) * 2048 + t;
        int src[4], dst[4], pos[4];
        #pragma unroll
        for (int k = 0; k < 4; ++k) {
            int e = base + k * 512;
            bool v = (e < N_EDGES);
            dst[k] = v ? edges[N_EDGES + e] : 0;
            src[k] = v ? edges[e] : 0;
        }
        #pragma unroll
        for (int k = 0; k < 4; ++k) {
            int e = base + k * 512;
            if (e < N_EDGES)
                pos[k] = atomicAdd(&cursor[(size_t)dst[k] * CSTRIDE], 1);
        }
        #pragma unroll
        for (int k = 0; k < 4; ++k) {
            int e = base + k * 512;
            if (e < N_EDGES && pos[k] < MAXDEG)
                col[dst[k] * MAXDEG + pos[k]] = src[k];
        }
        return;
    }
    int m0 = b * 64;

    int ga = t >> 7, hq = (t >> 6) & 1, la = t & 63;
    int nodeA = m0 + ga * 16 + (la & 15);
    if (nodeA >= N_NODES) nodeA = N_NODES - 1;
    const float* Asrc = A + (size_t)nodeA * IN_CH + (la >> 4) * 8 + hq * 4;
    const uint4* Wg = (const uint4*)Wpk;
    int tb = t & ~63;                 // wave-uniform LDS slot base

    int w = t >> 6, lane = t & 63;
    int wm = w >> 2, wn = w & 3;
    int l15 = lane & 15, q = lane >> 4;

    f32x4 acc[4][2] = {};

    // prologue: stage chunk 0 -> buf0, chunk 1 -> buf1 (6 loads in flight)
    gload16(Wg + t,        &LDS[0][tb]);
    gload16(Wg + 512 + t,  &LDS[0][512 + tb]);
    gload16(Asrc,          &LDS[0][1024 + tb]);
    gload16(Wg + 1024 + t,       &LDS[1][tb]);
    gload16(Wg + 1024 + 512 + t, &LDS[1][512 + tb]);
    gload16(Asrc + 32,           &LDS[1][1024 + tb]);

    #define COMPUTE(bc)                                                           \
    {                                                                             \
        bf16x8 wf[4];                                                             \
        _Pragma("unroll")                                                         \
        for (int i = 0; i < 4; ++i)                                               \
            wf[i] = *(const bf16x8*)&LDS[bc][(wn * 4 + i) * 64 + lane];           \
        bf16x8 af[2];                                                             \
        _Pragma("unroll")                                                         \
        for (int g2 = 0; g2 < 2; ++g2) {                                          \
            f32x4 lo = *(const f32x4*)&LDS[bc][1024 + ((wm * 2 + g2) * 2 + 0) * 64 + lane]; \
            f32x4 hi = *(const f32x4*)&LDS[bc][1024 + ((wm * 2 + g2) * 2 + 1) * 64 + lane]; \
            uint4 pk;                                                             \
            pk.x = cvtpk(lo[0], lo[1]); pk.y = cvtpk(lo[2], lo[3]);               \
            pk.z = cvtpk(hi[0], hi[1]); pk.w = cvtpk(hi[2], hi[3]);               \
            af[g2] = __builtin_bit_cast(bf16x8, pk);                              \
        }                                                                         \
        _Pragma("unroll")                                                         \
        for (int i = 0; i < 4; ++i)                                               \
            _Pragma("unroll")                                                     \
            for (int g2 = 0; g2 < 2; ++g2)                                        \
                acc[i][g2] = __builtin_amdgcn_mfma_f32_16x16x32_bf16(wf[i], af[g2], acc[i][g2], 0, 0, 0); \
    }

    int bc = 0, bs = 2;               // compute buf, stage buf
    for (int c = 0; c < 30; ++c) {
        const uint4* ws = Wg + (size_t)(c + 2) * 1024;
        gload16(ws + t,       &LDS[bs][tb]);
        gload16(ws + 512 + t, &LDS[bs][512 + tb]);
        gload16(Asrc + (size_t)(c + 2) * 32, &LDS[bs][1024 + tb]);
        asm volatile("s_waitcnt vmcnt(6)" ::: "memory");
        __builtin_amdgcn_sched_barrier(0);
        __builtin_amdgcn_s_barrier();
        __builtin_amdgcn_sched_barrier(0);
        COMPUTE(bc);
        __builtin_amdgcn_s_barrier();
        __builtin_amdgcn_sched_barrier(0);
        bc = (bc == 2) ? 0 : bc + 1;
        bs = (bs == 2) ? 0 : bs + 1;
    }
    asm volatile("s_waitcnt vmcnt(3)" ::: "memory");
    __builtin_amdgcn_sched_barrier(0);
    __builtin_amdgcn_s_barrier();
    __builtin_amdgcn_sched_barrier(0);
    COMPUTE(bc);
    bc = (bc == 2) ? 0 : bc + 1;
    asm volatile("s_waitcnt vmcnt(0)" ::: "memory");
    __builtin_amdgcn_sched_barrier(0);
    __builtin_amdgcn_s_barrier();
    __builtin_amdgcn_sched_barrier(0);
    COMPUTE(bc);
    #undef COMPUTE

    #pragma unroll
    for (int g2 = 0; g2 < 2; ++g2) {
        int node = m0 + wm * 32 + g2 * 16 + l15;
        if (node < N_NODES) {
            ushort* base = (wn < 2) ? (Py + (size_t)node * FC + (wn & 1) * 64 + q * 4)
                                    : (Pz + (size_t)node * FC + (wn & 1) * 64 + q * 4);
            #pragma unroll
            for (int i = 0; i < 4; ++i) {
                f32x4 v = acc[i][g2];
                uint2 pk;
                pk.x = cvtpk(v[0], v[1]);
                pk.y = cvtpk(v[2], v[3]);
                *(uint2*)(base + i * 16) = pk;
            }
        }
    }
}

// ---------------- fused tail v4: 8 nodes/block + batched windows ------------
// R8-vs-R12/13 accounting: the plain 8-node/block tail (3125 blocks, ~32
// waves/CU TLP) beats the 32-node restructures -- TLP > W1s amortization for
// this latency-bound gather. v4 keeps the R8 shape and adds R13's proven
// batching along the window axis: each wave (1 node) issues ALL 4 gather
// windows (<=16 uint4 in flight, 4x Little's law) before consuming.
// Window guard (win*16 < d) is wave-uniform -> no divergence.
__global__ __launch_bounds__(512, 4) void fused_tail(const ushort* __restrict__ Py,
                                                     const ushort* __restrict__ Pz,
                                                     const int* __restrict__ deg,
                                                     const int* __restrict__ col,
                                                     const float* __restrict__ addf,
                                                     const float* __restrict__ bl,
                                                     const float* __restrict__ W1,
                                                     const float* __restrict__ b1,
                                                     const float* __restrict__ W2,
                                                     const float* __restrict__ b2,
                                                     const float* __restrict__ gamma,
                                                     const float* __restrict__ beta,
                                                     const float* __restrict__ rmean,
                                                     const float* __restrict__ rvar,
                                                     float* __restrict__ out) {
    __shared__ float W1s[XCH][MID + 3];
    __shared__ float xbuf[8][XCH + 4];
    __shared__ float hbuf[8][MID + 3];
    int t = threadIdx.x;
    for (int idx = t; idx < MID * XCH; idx += 512) {
        int j = idx / XCH, k = idx - j * XCH;
        W1s[k][j] = W1[idx];
    }
    __syncthreads();
    int w = t >> 6, lane = t & 63;
    int n = blockIdx.x * 8 + w;
    bool valid = (n < N_NODES);
    int d = valid ? deg[(size_t)n * CSTRIDE] : 0;
    if (d > MAXDEG) d = MAXDEG;
    int g = lane >> 4, c16 = lane & 15;
    float s[8] = {0.f, 0.f, 0.f, 0.f, 0.f, 0.f, 0.f, 0.f};
    if (d > 0) {
        int cidx = col[n * MAXDEG + (lane < d ? lane : 0)];
        // issue ALL windows' loads before consuming (<=16 uint4 in flight)
        uint4 v[4][4];
        int nw = (d + 15) >> 4;       // wave-uniform window count
        #pragma unroll
        for (int win = 0; win < 4; ++win) {
            if (win < nw) {
                #pragma unroll
                for (int j = 0; j < 4; ++j) {
                    int ee = win * 16 + g + j * 4;
                    int e = __shfl(cidx, (ee < d) ? ee : 0);
                    v[win][j] = *(const uint4*)&Py[(size_t)e * FC + c16 * 8];
                }
            }
        }
        #pragma unroll
        for (int win = 0; win < 4; ++win) {
            if (win < nw) {
                #pragma unroll
                for (int j = 0; j < 4; ++j) {
                    if (win * 16 + g + j * 4 < d) {
                        s[0] += bflo(v[win][j].x); s[1] += bfhi(v[win][j].x);
                        s[2] += bflo(v[win][j].y); s[3] += bfhi(v[win][j].y);
                        s[4] += bflo(v[win][j].z); s[5] += bfhi(v[win][j].z);
                        s[6] += bflo(v[win][j].w); s[7] += bfhi(v[win][j].w);
                    }
                }
            }
        }
        #pragma unroll
        for (int r = 0; r < 8; ++r) {
            s[r] += __shfl_xor(s[r], 16);
            s[r] += __shfl_xor(s[r], 32);
        }
    }
    if (valid) {
        if (lane < 16) {
            #pragma unroll
            for (int r = 0; r < 8; ++r) xbuf[w][lane * 8 + r] = s[r];
        }
        float invd = 1.0f / (float)(d > 1 ? d : 1);
        unsigned int vr = *(const unsigned int*)&Pz[(size_t)n * FC + lane * 2];
        float x0 = xbuf[w][2 * lane] * invd + bl[2 * lane] + bflo(vr);
        float x1 = xbuf[w][2 * lane + 1] * invd + bl[2 * lane + 1] + bfhi(vr);
        x0 = (x0 >= 0.f) ? x0 : 0.01f * x0;
        x1 = (x1 >= 0.f) ? x1 : 0.01f * x1;
        xbuf[w][2 * lane] = x0;
        xbuf[w][2 * lane + 1] = x1;
        if (lane < ADD_CH) xbuf[w][FC + lane] = addf[(size_t)n * ADD_CH + lane];
        if (lane < MID) {
            float h = b1[lane];
            #pragma unroll 4
            for (int k = 0; k < XCH; ++k) h += W1s[k][lane] * xbuf[w][k];
            h = fmaxf(h, 0.0f);
            h = gamma[lane] * (h - rmean[lane]) * rsqrtf(rvar[lane] + 1e-5f) + beta[lane];
            hbuf[w][lane] = h;
        }
        if (lane < OUT_CH) {
            float o = b2[lane];
            #pragma unroll
            for (int j = 0; j < MID; ++j) o += W2[lane * MID + j] * hbuf[w][j];
            out[(size_t)n * OUT_CH + lane] = o;
        }
    }
}

// ---------------- launch ----------------

extern "C" void kernel_launch(void* const* d_in, const int* in_sizes, int n_in,
                              void* d_out, int out_size, void* d_ws, size_t ws_size,
                              hipStream_t stream) {
    const float* features = (const float*)d_in[0];
    const int*   edges    = (const int*)d_in[1];
    const float* addf     = (const float*)d_in[4];
    const float* Wl       = (const float*)d_in[5];
    const float* bl       = (const float*)d_in[6];
    const float* Wr       = (const float*)d_in[7];
    const float* W1       = (const float*)d_in[8];
    const float* b1       = (const float*)d_in[9];
    const float* W2       = (const float*)d_in[10];
    const float* b2       = (const float*)d_in[11];
    const float* gamma    = (const float*)d_in[12];
    const float* beta     = (const float*)d_in[13];
    const float* rmean    = (const float*)d_in[14];
    const float* rvar     = (const float*)d_in[15];
    float* out = (float*)d_out;

    char* ws = (char*)d_ws;
    size_t off = 0;
    ushort* Py = (ushort*)(ws + off);     off += (size_t)N_NODES * FC * 2;            // 6.4 MB
    ushort* Pz = (ushort*)(ws + off);     off += (size_t)N_NODES * FC * 2;            // 6.4 MB
    ushort* Wpk = (ushort*)(ws + off);    off += (size_t)32 * 16 * 64 * 16;           // 512 KB
    int* cursor = (int*)(ws + off);       off += (size_t)N_NODES * CSTRIDE * 4;       // 1.6 MB
    int* col = (int*)(ws + off);          off += (size_t)N_NODES * MAXDEG * 4;        // 6.4 MB

    prep<<<WSWZ_B + ZERO_B, 512, 0, stream>>>(Wl, Wr, Wpk, cursor);

    gemm_build<<<GEMM_B + BUILD_B, 512, 0, stream>>>(features, Wpk, Py, Pz,
                                                     edges, cursor, col);

    fused_tail<<<(N_NODES + 7) / 8, 512, 0, stream>>>(Py, Pz, cursor, col, addf, bl,
                                                      W1, b1, W2, b2, gamma, beta,
                                                      rmean, rvar, out);
}

// Round 15
// 254.935 us; speedup vs baseline: 1.0381x; 1.0381x over previous
//
#include <hip/hip_runtime.h>

#define N_NODES 25000
#define N_EDGES 400000
#define IN_CH 1024
#define FC 128
#define ADD_CH 20
#define XCH 148   // FC + ADD
#define MID 37
#define OUT_CH 3
#define MAXDEG 64
#define CSTRIDE 16   // cursor padded to one counter per 64B line

typedef short bf16x8 __attribute__((ext_vector_type(8)));
typedef float f32x4 __attribute__((ext_vector_type(4)));

__device__ __forceinline__ float bflo(unsigned int v) {
    return __builtin_bit_cast(float, v << 16);
}
__device__ __forceinline__ float bfhi(unsigned int v) {
    return __builtin_bit_cast(float, v & 0xffff0000u);
}
// pack 2 f32 -> 2 bf16 (RNE), single VALU op
__device__ __forceinline__ unsigned int cvtpk(float a, float b) {
    unsigned int r;
    asm("v_cvt_pk_bf16_f32 %0, %1, %2" : "=v"(r) : "v"(a), "v"(b));
    return r;
}

// async 16B global->LDS DMA (counts in vmcnt)
__device__ __forceinline__ void gload16(const void* g, void* l) {
    __builtin_amdgcn_global_load_lds(
        (const __attribute__((address_space(1))) unsigned int*)g,
        (__attribute__((address_space(3))) unsigned int*)l,
        16, 0, 0);
}

// ---------------- prep: W swizzle + cursor zero (one dispatch) --------------
#define WSWZ_B 16
#define ZERO_B 49   // 49*512 >= 25000 (each thread zeroes one padded line)

__global__ __launch_bounds__(512) void prep(const float* __restrict__ Wl,
                                            const float* __restrict__ Wr,
                                            ushort* __restrict__ Wpk,
                                            int* __restrict__ cursor) {
    int b = blockIdx.x, t = threadIdx.x;
    if (b < WSWZ_B) {
        int w = t >> 6, lane = t & 63, l15 = lane & 15, q8 = (lane >> 4) * 8;
        int ch = b * 16 + l15;
        const float* src = (ch < FC) ? (Wl + (size_t)ch * IN_CH)
                                     : (Wr + (size_t)(ch - FC) * IN_CH);
        #pragma unroll
        for (int j = 0; j < 4; ++j) {
            int kt = w * 4 + j;
            float4 lo = *(const float4*)(src + kt * 32 + q8);
            float4 hi = *(const float4*)(src + kt * 32 + q8 + 4);
            uint4 pk;
            pk.x = cvtpk(lo.x, lo.y); pk.y = cvtpk(lo.z, lo.w);
            pk.z = cvtpk(hi.x, hi.y); pk.w = cvtpk(hi.z, hi.w);
            ((uint4*)Wpk)[((size_t)kt * 16 + b) * 64 + lane] = pk;
        }
    } else {
        int i = (b - WSWZ_B) * 512 + t;
        if (i < N_NODES) {
            uint4 z = {0, 0, 0, 0};
            uint4* dst = (uint4*)(cursor + (size_t)i * CSTRIDE);
            dst[0] = z; dst[1] = z; dst[2] = z; dst[3] = z;
        }
    }
}

// ---------------- hetero: depth-3 counted-vmcnt GEMM + ILP build ------------
// UNCHANGED (round-8 config, reproduced 64-66us across 4 runs; locally
// converged after 12 variant rounds bracketed it 62-84us).
#define GEMM_B 391    // ceil(25000/64)
#define BUILD_B 196   // ceil(400000/2048)

__global__ __launch_bounds__(512, 4) void gemm_build(const float* __restrict__ A,
                                                     const ushort* __restrict__ Wpk,
                                                     ushort* __restrict__ Py,
                                                     ushort* __restrict__ Pz,
                                                     const int* __restrict__ edges,
                                                     int* __restrict__ cursor,
                                                     int* __restrict__ col) {
    __shared__ uint4 LDS[3][1536];   // [buf][ 0..1023 = W | 1024..1535 = A ]  72 KB
    int b = blockIdx.x, t = threadIdx.x;
    if (b >= GEMM_B) {
        int base = (b - GEMM_B) * 2048 + t;
        int src[4], dst[4], pos[4];
        #pragma unroll
        for (int k = 0; k < 4; ++k) {
            int e = base + k * 512;
            bool v = (e < N_EDGES);
            dst[k] = v ? edges[N_EDGES + e] : 0;
            src[k] = v ? edges[e] : 0;
        }
        #pragma unroll
        for (int k = 0; k < 4; ++k) {
            int e = base + k * 512;
            if (e < N_EDGES)
                pos[k] = atomicAdd(&cursor[(size_t)dst[k] * CSTRIDE], 1);
        }
        #pragma unroll
        for (int k = 0; k < 4; ++k) {
            int e = base + k * 512;
            if (e < N_EDGES && pos[k] < MAXDEG)
                col[dst[k] * MAXDEG + pos[k]] = src[k];
        }
        return;
    }
    int m0 = b * 64;

    int ga = t >> 7, hq = (t >> 6) & 1, la = t & 63;
    int nodeA = m0 + ga * 16 + (la & 15);
    if (nodeA >= N_NODES) nodeA = N_NODES - 1;
    const float* Asrc = A + (size_t)nodeA * IN_CH + (la >> 4) * 8 + hq * 4;
    const uint4* Wg = (const uint4*)Wpk;
    int tb = t & ~63;                 // wave-uniform LDS slot base

    int w = t >> 6, lane = t & 63;
    int wm = w >> 2, wn = w & 3;
    int l15 = lane & 15, q = lane >> 4;

    f32x4 acc[4][2] = {};

    // prologue: stage chunk 0 -> buf0, chunk 1 -> buf1 (6 loads in flight)
    gload16(Wg + t,        &LDS[0][tb]);
    gload16(Wg + 512 + t,  &LDS[0][512 + tb]);
    gload16(Asrc,          &LDS[0][1024 + tb]);
    gload16(Wg + 1024 + t,       &LDS[1][tb]);
    gload16(Wg + 1024 + 512 + t, &LDS[1][512 + tb]);
    gload16(Asrc + 32,           &LDS[1][1024 + tb]);

    #define COMPUTE(bc)                                                           \
    {                                                                             \
        bf16x8 wf[4];                                                             \
        _Pragma("unroll")                                                         \
        for (int i = 0; i < 4; ++i)                                               \
            wf[i] = *(const bf16x8*)&LDS[bc][(wn * 4 + i) * 64 + lane];           \
        bf16x8 af[2];                                                             \
        _Pragma("unroll")                                                         \
        for (int g2 = 0; g2 < 2; ++g2) {                                          \
            f32x4 lo = *(const f32x4*)&LDS[bc][1024 + ((wm * 2 + g2) * 2 + 0) * 64 + lane]; \
            f32x4 hi = *(const f32x4*)&LDS[bc][1024 + ((wm * 2 + g2) * 2 + 1) * 64 + lane]; \
            uint4 pk;                                                             \
            pk.x = cvtpk(lo[0], lo[1]); pk.y = cvtpk(lo[2], lo[3]);               \
            pk.z = cvtpk(hi[0], hi[1]); pk.w = cvtpk(hi[2], hi[3]);               \
            af[g2] = __builtin_bit_cast(bf16x8, pk);                              \
        }                                                                         \
        _Pragma("unroll")                                                         \
        for (int i = 0; i < 4; ++i)                                               \
            _Pragma("unroll")                                                     \
            for (int g2 = 0; g2 < 2; ++g2)                                        \
                acc[i][g2] = __builtin_amdgcn_mfma_f32_16x16x32_bf16(wf[i], af[g2], acc[i][g2], 0, 0, 0); \
    }

    int bc = 0, bs = 2;               // compute buf, stage buf
    for (int c = 0; c < 30; ++c) {
        const uint4* ws = Wg + (size_t)(c + 2) * 1024;
        gload16(ws + t,       &LDS[bs][tb]);
        gload16(ws + 512 + t, &LDS[bs][512 + tb]);
        gload16(Asrc + (size_t)(c + 2) * 32, &LDS[bs][1024 + tb]);
        asm volatile("s_waitcnt vmcnt(6)" ::: "memory");
        __builtin_amdgcn_sched_barrier(0);
        __builtin_amdgcn_s_barrier();
        __builtin_amdgcn_sched_barrier(0);
        COMPUTE(bc);
        __builtin_amdgcn_s_barrier();
        __builtin_amdgcn_sched_barrier(0);
        bc = (bc == 2) ? 0 : bc + 1;
        bs = (bs == 2) ? 0 : bs + 1;
    }
    asm volatile("s_waitcnt vmcnt(3)" ::: "memory");
    __builtin_amdgcn_sched_barrier(0);
    __builtin_amdgcn_s_barrier();
    __builtin_amdgcn_sched_barrier(0);
    COMPUTE(bc);
    bc = (bc == 2) ? 0 : bc + 1;
    asm volatile("s_waitcnt vmcnt(0)" ::: "memory");
    __builtin_amdgcn_sched_barrier(0);
    __builtin_amdgcn_s_barrier();
    __builtin_amdgcn_sched_barrier(0);
    COMPUTE(bc);
    #undef COMPUTE

    #pragma unroll
    for (int g2 = 0; g2 < 2; ++g2) {
        int node = m0 + wm * 32 + g2 * 16 + l15;
        if (node < N_NODES) {
            ushort* base = (wn < 2) ? (Py + (size_t)node * FC + (wn & 1) * 64 + q * 4)
                                    : (Pz + (size_t)node * FC + (wn & 1) * 64 + q * 4);
            #pragma unroll
            for (int i = 0; i < 4; ++i) {
                f32x4 v = acc[i][g2];
                uint2 pk;
                pk.x = cvtpk(v[0], v[1]);
                pk.y = cvtpk(v[2], v[3]);
                *(uint2*)(base + i * 16) = pk;
            }
        }
    }
}

// ---------------- fused tail v5: gather-first phase order -------------------
// R8 shape exactly (8 nodes/block, 512 thr, serial windows -- the form that
// beat all restructures), but PHASES REORDERED: the gather/reduce/epilogue-x
// work is wave-private (xbuf[w] only) and never needed W1s, yet R8 paid
// {W1s fill + barrier} (~2000cy) before the first dependent load (deg->col->
// Py). v5: (1) gather+reduce+x-build first (loads start at cycle 0),
// (2) W1s fill, (3) one barrier, (4) MLP+store. Fill overlaps other waves'
// gathers via TLP; barrier sits behind latency-bound work instead of ahead.
__global__ __launch_bounds__(512) void fused_tail(const ushort* __restrict__ Py,
                                                  const ushort* __restrict__ Pz,
                                                  const int* __restrict__ deg,
                                                  const int* __restrict__ col,
                                                  const float* __restrict__ addf,
                                                  const float* __restrict__ bl,
                                                  const float* __restrict__ W1,
                                                  const float* __restrict__ b1,
                                                  const float* __restrict__ W2,
                                                  const float* __restrict__ b2,
                                                  const float* __restrict__ gamma,
                                                  const float* __restrict__ beta,
                                                  const float* __restrict__ rmean,
                                                  const float* __restrict__ rvar,
                                                  float* __restrict__ out) {
    __shared__ float W1s[XCH][MID + 3];
    __shared__ float xbuf[8][XCH + 4];
    __shared__ float hbuf[8][MID + 3];
    int t = threadIdx.x;
    int w = t >> 6, lane = t & 63;
    int n = blockIdx.x * 8 + w;
    bool valid = (n < N_NODES);

    // ---- phase 1: gather + reduce + x-build (wave-private, no barrier) ----
    int d = valid ? deg[(size_t)n * CSTRIDE] : 0;
    if (d > MAXDEG) d = MAXDEG;
    int g = lane >> 4, c16 = lane & 15;
    float s[8] = {0.f, 0.f, 0.f, 0.f, 0.f, 0.f, 0.f, 0.f};
    if (d > 0) {
        int cidx = col[n * MAXDEG + (lane < d ? lane : 0)];
        for (int i = 0; i < d; i += 16) {
            int e[4];
            uint4 v[4];
            #pragma unroll
            for (int j = 0; j < 4; ++j) {
                int ee = i + g + j * 4;
                e[j] = __shfl(cidx, (ee < d) ? ee : 0);
            }
            #pragma unroll
            for (int j = 0; j < 4; ++j)
                v[j] = *(const uint4*)&Py[(size_t)e[j] * FC + c16 * 8];
            #pragma unroll
            for (int j = 0; j < 4; ++j) {
                if (i + g + j * 4 < d) {
                    s[0] += bflo(v[j].x); s[1] += bfhi(v[j].x);
                    s[2] += bflo(v[j].y); s[3] += bfhi(v[j].y);
                    s[4] += bflo(v[j].z); s[5] += bfhi(v[j].z);
                    s[6] += bflo(v[j].w); s[7] += bfhi(v[j].w);
                }
            }
        }
        #pragma unroll
        for (int r = 0; r < 8; ++r) {
            s[r] += __shfl_xor(s[r], 16);
            s[r] += __shfl_xor(s[r], 32);
        }
    }
    if (valid) {
        if (lane < 16) {
            #pragma unroll
            for (int r = 0; r < 8; ++r) xbuf[w][lane * 8 + r] = s[r];
        }
        float invd = 1.0f / (float)(d > 1 ? d : 1);
        unsigned int vr = *(const unsigned int*)&Pz[(size_t)n * FC + lane * 2];
        float x0 = xbuf[w][2 * lane] * invd + bl[2 * lane] + bflo(vr);
        float x1 = xbuf[w][2 * lane + 1] * invd + bl[2 * lane + 1] + bfhi(vr);
        x0 = (x0 >= 0.f) ? x0 : 0.01f * x0;
        x1 = (x1 >= 0.f) ? x1 : 0.01f * x1;
        xbuf[w][2 * lane] = x0;
        xbuf[w][2 * lane + 1] = x1;
        if (lane < ADD_CH) xbuf[w][FC + lane] = addf[(size_t)n * ADD_CH + lane];
    }

    // ---- phase 2: W1s fill (overlaps other waves' gathers via TLP) ----
    for (int idx = t; idx < MID * XCH; idx += 512) {
        int j = idx / XCH, k = idx - j * XCH;
        W1s[k][j] = W1[idx];
    }
    __syncthreads();

    // ---- phase 3: MLP + store ----
    if (valid) {
        if (lane < MID) {
            float h = b1[lane];
            #pragma unroll 4
            for (int k = 0; k < XCH; ++k) h += W1s[k][lane] * xbuf[w][k];
            h = fmaxf(h, 0.0f);
            h = gamma[lane] * (h - rmean[lane]) * rsqrtf(rvar[lane] + 1e-5f) + beta[lane];
            hbuf[w][lane] = h;
        }
        if (lane < OUT_CH) {
            float o = b2[lane];
            #pragma unroll
            for (int j = 0; j < MID; ++j) o += W2[lane * MID + j] * hbuf[w][j];
            out[(size_t)n * OUT_CH + lane] = o;
        }
    }
}

// ---------------- launch ----------------

extern "C" void kernel_launch(void* const* d_in, const int* in_sizes, int n_in,
                              void* d_out, int out_size, void* d_ws, size_t ws_size,
                              hipStream_t stream) {
    const float* features = (const float*)d_in[0];
    const int*   edges    = (const int*)d_in[1];
    const float* addf     = (const float*)d_in[4];
    const float* Wl       = (const float*)d_in[5];
    const float* bl       = (const float*)d_in[6];
    const float* Wr       = (const float*)d_in[7];
    const float* W1       = (const float*)d_in[8];
    const float* b1       = (const float*)d_in[9];
    const float* W2       = (const float*)d_in[10];
    const float* b2       = (const float*)d_in[11];
    const float* gamma    = (const float*)d_in[12];
    const float* beta     = (const float*)d_in[13];
    const float* rmean    = (const float*)d_in[14];
    const float* rvar     = (const float*)d_in[15];
    float* out = (float*)d_out;

    char* ws = (char*)d_ws;
    size_t off = 0;
    ushort* Py = (ushort*)(ws + off);     off += (size_t)N_NODES * FC * 2;            // 6.4 MB
    ushort* Pz = (ushort*)(ws + off);     off += (size_t)N_NODES * FC * 2;            // 6.4 MB
    ushort* Wpk = (ushort*)(ws + off);    off += (size_t)32 * 16 * 64 * 16;           // 512 KB
    int* cursor = (int*)(ws + off);       off += (size_t)N_NODES * CSTRIDE * 4;       // 1.6 MB
    int* col = (int*)(ws + off);          off += (size_t)N_NODES * MAXDEG * 4;        // 6.4 MB

    prep<<<WSWZ_B + ZERO_B, 512, 0, stream>>>(Wl, Wr, Wpk, cursor);

    gemm_build<<<GEMM_B + BUILD_B, 512, 0, stream>>>(features, Wpk, Py, Pz,
                                                     edges, cursor, col);

    fused_tail<<<(N_NODES + 7) / 8, 512, 0, stream>>>(Py, Pz, cursor, col, addf, bl,
                                                      W1, b1, W2, b2, gamma, beta,
                                                      rmean, rvar, out);
}